// Round 8
// baseline (87.175 us; speedup 1.0000x reference)
//
#include <hip/hip_runtime.h>
#include <stdint.h>

// MX fp8_e4m3 fake-quantize, group=32 along last dim (8192x8192 f32).
// DISCRIMINATING PROBE: all-nontemporal (nt loads AND nt stores).
// If time stays ~81-86us while FETCH doubles -> fabric-capped (roofline).
// If time regresses to ~100+us -> DRAM-capped, L3 hit rate is the lever.

typedef float f32x4 __attribute__((ext_vector_type(4)));

// DPP max combine. CTRL: 0xB1 = quad_perm xor1, 0x4E = quad_perm xor2,
// 0x141 = row_half_mirror (lane ^ 7 within 8-lane half-row).
template <int CTRL>
__device__ __forceinline__ float dpp_fmax(float x) {
    int y = __builtin_amdgcn_update_dpp(0, __float_as_int(x), CTRL, 0xF, 0xF, true);
    return fmaxf(x, __int_as_float(y));
}

__device__ __forceinline__ float group_scale(float a) {
    // a = group absmax (>= 0). se = floor(log2(a)) - 8 via exponent bits;
    // scale = max(2^se, 1e-5); exponent clips fold into the 1e-5 floor.
    int me = (int)(__float_as_uint(a) >> 23);  // biased exponent
    int se = me - 135;                         // zero -> -135
    return (se < -16) ? 1e-5f : __uint_as_float((uint32_t)(se + 127) << 23);
}

__device__ __forceinline__ float mx_quant_elem(float xx, float inv, float scale) {
    float v  = xx * inv;               // x / scale (exact: pow2 scale)
    float av = fabsf(v);
    int e = (int)(__float_as_uint(av) >> 23) - 127;   // zero/denorm -> -127
    e = (e < -6) ? -6 : e;                             // min normal exp
    float sc    = __uint_as_float((uint32_t)(130 - e) << 23);  // 2^(3-e)
    float scinv = __uint_as_float((uint32_t)(124 + e) << 23);  // 2^(e-3)
    float r = floorf(fmaf(av, sc, 0.5f));  // nearest, half away from zero
    r = r * scinv;
    r = fminf(r, 448.0f);                  // saturate e4m3
    return copysignf(r, v) * scale;
}

__device__ __forceinline__ f32x4 process4(f32x4 v) {
    float a = fmaxf(fmaxf(fabsf(v[0]), fabsf(v[1])),
                    fmaxf(fabsf(v[2]), fabsf(v[3])));
    a = dpp_fmax<0xB1>(a);    // xor 1
    a = dpp_fmax<0x4E>(a);    // xor 2
    a = dpp_fmax<0x141>(a);   // xor 7 -> max over the 8-lane group
    float scale = group_scale(a);
    float inv   = 1.0f / scale;
    f32x4 r;
    r[0] = mx_quant_elem(v[0], inv, scale);
    r[1] = mx_quant_elem(v[1], inv, scale);
    r[2] = mx_quant_elem(v[2], inv, scale);
    r[3] = mx_quant_elem(v[3], inv, scale);
    return r;
}

__global__ void __launch_bounds__(256) mxq_kernel(const f32x4* __restrict__ x4,
                                                  f32x4* __restrict__ o4) {
    // One trip per block: 1024 contiguous vec4s (16 KiB), lane at
    // tid + {0,256,512,768} -> 4 fully coalesced 1 KiB/wave loads.
    int i = blockIdx.x * 1024 + threadIdx.x;
    f32x4 v0 = __builtin_nontemporal_load(&x4[i]);
    f32x4 v1 = __builtin_nontemporal_load(&x4[i + 256]);
    f32x4 v2 = __builtin_nontemporal_load(&x4[i + 512]);
    f32x4 v3 = __builtin_nontemporal_load(&x4[i + 768]);
    f32x4 r0 = process4(v0);
    f32x4 r1 = process4(v1);
    f32x4 r2 = process4(v2);
    f32x4 r3 = process4(v3);
    __builtin_nontemporal_store(r0, &o4[i]);
    __builtin_nontemporal_store(r1, &o4[i + 256]);
    __builtin_nontemporal_store(r2, &o4[i + 512]);
    __builtin_nontemporal_store(r3, &o4[i + 768]);
}

extern "C" void kernel_launch(void* const* d_in, const int* in_sizes, int n_in,
                              void* d_out, int out_size, void* d_ws, size_t ws_size,
                              hipStream_t stream) {
    const f32x4* x4 = (const f32x4*)d_in[0];
    f32x4* o4       = (f32x4*)d_out;
    int n      = in_sizes[0];           // 67,108,864 (exactly 16384 * 4096)
    int blocks = n >> 12;               // 4096 elems (1024 vec4) per block
    mxq_kernel<<<blocks, 256, 0, stream>>>(x4, o4);
}

// Round 9
// 81.545 us; speedup vs baseline: 1.0690x; 1.0690x over previous
//
#include <hip/hip_runtime.h>
#include <stdint.h>

// MX fp8_e4m3 fake-quantize, group=32 along last dim (8192x8192 f32).
// BEST CONFIG (R6, 81.2 us): 4 elems/lane coalesced float4, 8-lane groups,
// DPP-only reduction, cacheable loads (input stays ~50% L3-resident across
// graph replays), nontemporal stores (write stream doesn't churn L3),
// one 16 KiB tile per block (no loop -> no store->load vmcnt coupling).
// Measured regime: XCD<->MALL fabric-capped at ~6.6-6.8 TB/s app-level;
// R7 (L3 pinning) neutral, R8 (all-nt) regressed to DRAM cap -> roofline.

typedef float f32x4 __attribute__((ext_vector_type(4)));

// DPP max combine. CTRL: 0xB1 = quad_perm xor1, 0x4E = quad_perm xor2,
// 0x141 = row_half_mirror (lane ^ 7 within 8-lane half-row).
template <int CTRL>
__device__ __forceinline__ float dpp_fmax(float x) {
    int y = __builtin_amdgcn_update_dpp(0, __float_as_int(x), CTRL, 0xF, 0xF, true);
    return fmaxf(x, __int_as_float(y));
}

__device__ __forceinline__ float group_scale(float a) {
    // a = group absmax (>= 0). se = floor(log2(a)) - 8 via exponent bits;
    // scale = max(2^se, 1e-5); exponent clips fold into the 1e-5 floor.
    int me = (int)(__float_as_uint(a) >> 23);  // biased exponent
    int se = me - 135;                         // zero -> -135
    return (se < -16) ? 1e-5f : __uint_as_float((uint32_t)(se + 127) << 23);
}

__device__ __forceinline__ float mx_quant_elem(float xx, float inv, float scale) {
    float v  = xx * inv;               // x / scale (exact: pow2 scale)
    float av = fabsf(v);
    int e = (int)(__float_as_uint(av) >> 23) - 127;   // zero/denorm -> -127
    e = (e < -6) ? -6 : e;                             // min normal exp
    float sc    = __uint_as_float((uint32_t)(130 - e) << 23);  // 2^(3-e)
    float scinv = __uint_as_float((uint32_t)(124 + e) << 23);  // 2^(e-3)
    float r = floorf(fmaf(av, sc, 0.5f));  // nearest, half away from zero
    r = r * scinv;
    r = fminf(r, 448.0f);                  // saturate e4m3
    return copysignf(r, v) * scale;
}

__device__ __forceinline__ f32x4 process4(f32x4 v) {
    float a = fmaxf(fmaxf(fabsf(v[0]), fabsf(v[1])),
                    fmaxf(fabsf(v[2]), fabsf(v[3])));
    a = dpp_fmax<0xB1>(a);    // xor 1
    a = dpp_fmax<0x4E>(a);    // xor 2
    a = dpp_fmax<0x141>(a);   // xor 7 -> max over the 8-lane group
    float scale = group_scale(a);
    float inv   = 1.0f / scale;
    f32x4 r;
    r[0] = mx_quant_elem(v[0], inv, scale);
    r[1] = mx_quant_elem(v[1], inv, scale);
    r[2] = mx_quant_elem(v[2], inv, scale);
    r[3] = mx_quant_elem(v[3], inv, scale);
    return r;
}

__global__ void __launch_bounds__(256) mxq_kernel(const f32x4* __restrict__ x4,
                                                  f32x4* __restrict__ o4) {
    // One trip per block: 1024 contiguous vec4s (16 KiB), lane at
    // tid + {0,256,512,768} -> 4 fully coalesced 1 KiB/wave loads.
    int i = blockIdx.x * 1024 + threadIdx.x;
    f32x4 v0 = x4[i];
    f32x4 v1 = x4[i + 256];
    f32x4 v2 = x4[i + 512];
    f32x4 v3 = x4[i + 768];
    f32x4 r0 = process4(v0);
    f32x4 r1 = process4(v1);
    f32x4 r2 = process4(v2);
    f32x4 r3 = process4(v3);
    __builtin_nontemporal_store(r0, &o4[i]);
    __builtin_nontemporal_store(r1, &o4[i + 256]);
    __builtin_nontemporal_store(r2, &o4[i + 512]);
    __builtin_nontemporal_store(r3, &o4[i + 768]);
}

extern "C" void kernel_launch(void* const* d_in, const int* in_sizes, int n_in,
                              void* d_out, int out_size, void* d_ws, size_t ws_size,
                              hipStream_t stream) {
    const f32x4* x4 = (const f32x4*)d_in[0];
    f32x4* o4       = (f32x4*)d_out;
    int n      = in_sizes[0];           // 67,108,864 (exactly 16384 * 4096)
    int blocks = n >> 12;               // 4096 elems (1024 vec4) per block
    mxq_kernel<<<blocks, 256, 0, stream>>>(x4, o4);
}